// Round 1
// baseline (1540.614 us; speedup 1.0000x reference)
//
#include <hip/hip_runtime.h>
#include <cstdint>

// Problem constants
#define GQ 4
#define KQ 1024
#define DQ 256     // = GQ * dq
#define dq 64
#define NQ 32768   // B*S = 8*4096
#define DECAYF 0.99f
#define EPSF 1e-5f

// Output flat offsets (floats)
#define OFF_ZQ    0
#define OFF_IND   8388608
#define OFF_EMB   8519680
#define OFF_CS    8781824
#define OFF_AVG   8785920

// Workspace layout (bytes)
#define WS_IND   0              // int32 [GQ][NQ]  (transposed ind)
#define WS_E2    524288         // float [GQ][KQ]
#define WS_TOT   540672         // float [GQ]
#define WS_CTR   540688         // int
#define WS_LIST  540696         // int2 [CAP]
#define CAP      8192

#define MARGIN 0.02f

__device__ __forceinline__ const float* uniform_ptr(const float* p) {
    uint64_t v = (uint64_t)p;
    uint32_t lo = __builtin_amdgcn_readfirstlane((uint32_t)v);
    uint32_t hi = __builtin_amdgcn_readfirstlane((uint32_t)(v >> 32));
    return (const float*)(((uint64_t)hi << 32) | lo);
}

// ---- e2[g][k] = sum_j embed[g][k][j]^2 ----
__global__ void k_e2(const float* __restrict__ embed, float* __restrict__ e2) {
    int t = blockIdx.x * blockDim.x + threadIdx.x; // 0..GQ*KQ-1
    const float* row = embed + (size_t)t * dq;
    float s = 0.f;
#pragma unroll
    for (int j = 0; j < dq; ++j) s = fmaf(row[j], row[j], s);
    e2[t] = s;
}

// ---- scores + argmax (top-2, flag near-ties) ----
__launch_bounds__(256)
__global__ void k_scores(const float* __restrict__ x, const float* __restrict__ embed,
                         const float* __restrict__ e2, int* __restrict__ ind_t,
                         int* __restrict__ ctr, int2* __restrict__ list) {
    int n = blockIdx.x * 256 + threadIdx.x;
    int g = blockIdx.y;

    float4 xr[16];
    const float4* xp = reinterpret_cast<const float4*>(x + (size_t)n * DQ + g * dq);
#pragma unroll
    for (int j = 0; j < 16; ++j) xr[j] = xp[j];

    const float* eb  = uniform_ptr(embed + (size_t)g * KQ * dq);
    const float* e2b = uniform_ptr(e2 + (size_t)g * KQ);

    float m1 = -3.4e38f, m2 = -3.4e38f;
    int k1 = 0;
    for (int k = 0; k < KQ; ++k) {
        const float4* er = reinterpret_cast<const float4*>(eb + k * dq);
        float a0 = 0.f, a1 = 0.f, a2 = 0.f, a3 = 0.f;
#pragma unroll
        for (int j = 0; j < 4; ++j) {
            float4 e0 = er[4 * j + 0], e1 = er[4 * j + 1];
            float4 e2v = er[4 * j + 2], e3 = er[4 * j + 3];
            float4 x0 = xr[4 * j + 0], x1 = xr[4 * j + 1];
            float4 x2v = xr[4 * j + 2], x3 = xr[4 * j + 3];
            a0 = fmaf(x0.x, e0.x, a0); a0 = fmaf(x0.y, e0.y, a0);
            a0 = fmaf(x0.z, e0.z, a0); a0 = fmaf(x0.w, e0.w, a0);
            a1 = fmaf(x1.x, e1.x, a1); a1 = fmaf(x1.y, e1.y, a1);
            a1 = fmaf(x1.z, e1.z, a1); a1 = fmaf(x1.w, e1.w, a1);
            a2 = fmaf(x2v.x, e2v.x, a2); a2 = fmaf(x2v.y, e2v.y, a2);
            a2 = fmaf(x2v.z, e2v.z, a2); a2 = fmaf(x2v.w, e2v.w, a2);
            a3 = fmaf(x3.x, e3.x, a3); a3 = fmaf(x3.y, e3.y, a3);
            a3 = fmaf(x3.z, e3.z, a3); a3 = fmaf(x3.w, e3.w, a3);
        }
        float dot = (a0 + a1) + (a2 + a3);
        float s = 2.0f * dot - e2b[k];
        bool gt1 = s > m1;
        float new_m2 = gt1 ? m1 : ((s > m2) ? s : m2);
        m1 = gt1 ? s : m1;
        k1 = gt1 ? k : k1;
        m2 = new_m2;
    }
    ind_t[(size_t)g * NQ + n] = k1;
    if (m1 - m2 < MARGIN) {
        int idx = atomicAdd(ctr, 1);
        if (idx < CAP) list[idx] = make_int2(n, g);
    }
}

// ---- f64 recheck of flagged queries ----
__launch_bounds__(256)
__global__ void k_recheck(const float* __restrict__ x, const float* __restrict__ embed,
                          const int* __restrict__ ctr, const int2* __restrict__ list,
                          int* __restrict__ ind_t) {
    __shared__ double sv[256];
    __shared__ int si[256];
    int nitems = *ctr;
    if (nitems > CAP) nitems = CAP;
    for (int it = blockIdx.x; it < nitems; it += gridDim.x) {
        int2 q = list[it];
        int n = q.x, g = q.y;
        const float* xrow = x + (size_t)n * DQ + g * dq;
        double best = -1e300;
        int bk = KQ;
        for (int k = threadIdx.x; k < KQ; k += 256) {
            const float* er = embed + ((size_t)g * KQ + k) * dq;
            double dot = 0.0, ee = 0.0;
#pragma unroll 8
            for (int j = 0; j < dq; ++j) {
                double ev = (double)er[j];
                dot = fma((double)xrow[j], ev, dot);
                ee = fma(ev, ev, ee);
            }
            double s = 2.0 * dot - ee;
            if (s > best || (s == best && k < bk)) { best = s; bk = k; }
        }
        sv[threadIdx.x] = best; si[threadIdx.x] = bk;
        __syncthreads();
        for (int off = 128; off > 0; off >>= 1) {
            if (threadIdx.x < off) {
                double ov = sv[threadIdx.x + off]; int oi = si[threadIdx.x + off];
                if (ov > sv[threadIdx.x] || (ov == sv[threadIdx.x] && oi < si[threadIdx.x])) {
                    sv[threadIdx.x] = ov; si[threadIdx.x] = oi;
                }
            }
            __syncthreads();
        }
        if (threadIdx.x == 0) ind_t[(size_t)g * NQ + n] = si[0];
        __syncthreads();
    }
}

// ---- zq gather + ind output ----
__global__ void k_gather(const float* __restrict__ embed, const int* __restrict__ ind_t,
                         float* __restrict__ zq, float* __restrict__ ind_out) {
    int t = blockIdx.x * 256 + threadIdx.x;   // 0 .. NQ*GQ*16-1 (float4 index)
    int j4 = t & 15;
    int g = (t >> 4) & 3;
    int n = t >> 6;
    int k = ind_t[(size_t)g * NQ + n];
    const float4* e4 = reinterpret_cast<const float4*>(embed) + ((size_t)(g * KQ + k) * 16 + j4);
    reinterpret_cast<float4*>(zq)[t] = *e4;
    if (t < NQ * GQ) {
        int n2 = t >> 2, g2 = t & 3;
        ind_out[t] = (float)ind_t[(size_t)g2 * NQ + n2];
    }
}

// ---- deterministic segment sum: counts + embed_sum; write ncs, nea ----
__launch_bounds__(64)
__global__ void k_segsum(const float* __restrict__ x, const int* __restrict__ ind_t,
                         const float* __restrict__ embed_avg, const float* __restrict__ cs,
                         float* __restrict__ out_cs, float* __restrict__ out_avg) {
    int gk = blockIdx.x;          // 0..GQ*KQ-1
    int g = gk >> 10, k = gk & 1023;
    int lane = threadIdx.x;       // 0..63 == dim j
    const int* ip = ind_t + (size_t)g * NQ;
    float acc = 0.f;
    int cnt = 0;
    for (int n0 = 0; n0 < NQ; n0 += 64) {
        int v = ip[n0 + lane];
        unsigned long long mask = __ballot(v == k);
        cnt += __popcll(mask);
        while (mask) {
            int i = __ffsll(mask) - 1;
            mask &= mask - 1;
            acc += x[(size_t)(n0 + i) * DQ + g * dq + lane];
        }
    }
    float nea = DECAYF * embed_avg[(size_t)gk * dq + lane] + (1.0f - DECAYF) * acc;
    out_avg[(size_t)gk * dq + lane] = nea;
    if (lane == 0) out_cs[gk] = DECAYF * cs[gk] + (1.0f - DECAYF) * (float)cnt;
}

// ---- tot[g] = sum_k ncs ----
__global__ void k_tot(const float* __restrict__ out_cs, float* __restrict__ tot) {
    int g = blockIdx.x;
    __shared__ float red[256];
    float s = 0.f;
    for (int k = threadIdx.x; k < KQ; k += 256) s += out_cs[g * KQ + k];
    red[threadIdx.x] = s;
    __syncthreads();
    for (int off = 128; off > 0; off >>= 1) {
        if (threadIdx.x < off) red[threadIdx.x] += red[threadIdx.x + off];
        __syncthreads();
    }
    if (threadIdx.x == 0) tot[g] = red[0];
}

// ---- new_embed = nea / smoothed ----
__global__ void k_embed(const float* __restrict__ out_avg, const float* __restrict__ out_cs,
                        const float* __restrict__ tot, float* __restrict__ out_embed) {
    int t = blockIdx.x * 256 + threadIdx.x;  // 0..GQ*KQ*dq-1
    int gk = t >> 6;
    int g = gk >> 10;
    double ncs = (double)out_cs[gk];
    double tt = (double)tot[g];
    double sm = (ncs + (double)EPSF) / (tt + (double)KQ * (double)EPSF) * tt;
    out_embed[t] = (float)((double)out_avg[t] / sm);
}

extern "C" void kernel_launch(void* const* d_in, const int* in_sizes, int n_in,
                              void* d_out, int out_size, void* d_ws, size_t ws_size,
                              hipStream_t stream) {
    const float* x         = (const float*)d_in[0];
    const float* embed     = (const float*)d_in[1];
    const float* embed_avg = (const float*)d_in[2];
    const float* cs        = (const float*)d_in[3];
    float* out = (float*)d_out;
    float* zq       = out + OFF_ZQ;
    float* ind_out  = out + OFF_IND;
    float* out_embed= out + OFF_EMB;
    float* out_cs   = out + OFF_CS;
    float* out_avg  = out + OFF_AVG;

    char* ws = (char*)d_ws;
    int*   ind_t = (int*)(ws + WS_IND);
    float* e2    = (float*)(ws + WS_E2);
    float* tot   = (float*)(ws + WS_TOT);
    int*   ctr   = (int*)(ws + WS_CTR);
    int2*  list  = (int2*)(ws + WS_LIST);

    hipMemsetAsync(ctr, 0, sizeof(int), stream);
    k_e2<<<GQ * KQ / 256, 256, 0, stream>>>(embed, e2);
    dim3 g1(NQ / 256, GQ);
    k_scores<<<g1, 256, 0, stream>>>(x, embed, e2, ind_t, ctr, list);
    k_recheck<<<256, 256, 0, stream>>>(x, embed, ctr, list, ind_t);
    k_gather<<<(NQ * GQ * 16) / 256, 256, 0, stream>>>(embed, ind_t, zq, ind_out);
    k_segsum<<<GQ * KQ, 64, 0, stream>>>(x, ind_t, embed_avg, cs, out_cs, out_avg);
    k_tot<<<GQ, 256, 0, stream>>>(out_cs, tot);
    k_embed<<<(GQ * KQ * dq) / 256, 256, 0, stream>>>(out_avg, out_cs, tot, out_embed);
}

// Round 2
// 573.567 us; speedup vs baseline: 2.6860x; 2.6860x over previous
//
#include <hip/hip_runtime.h>
#include <cstdint>

// Problem constants
#define GQ 4
#define KQ 1024
#define DQ 256     // = GQ * dq
#define dq 64
#define NQ 32768   // B*S = 8*4096
#define DECAYF 0.99f
#define EPSF 1e-5f

// Output flat offsets (floats)
#define OFF_ZQ    0
#define OFF_IND   8388608
#define OFF_EMB   8519680
#define OFF_CS    8781824
#define OFF_AVG   8785920

// Workspace layout (bytes)
#define WS_IND   0              // int32 [GQ][NQ]  (transposed ind)
#define WS_E2    524288         // float [GQ][KQ]
#define WS_EH    540672         // ushort(bf16) [GQ][KQ][dq]  embed hi
#define WS_EL    1064960        // ushort(bf16) [GQ][KQ][dq]  embed lo
#define WS_TOT   1589248        // float [GQ]
#define WS_CTR   1589264        // int
#define WS_LIST  1589280        // int2 [CAP]
#define CAP      16384

#define MARGIN 0.02f

#define MBLK 64    // rows per block
#define NW 4       // waves per block
#define WCOLS 256  // cols per wave
#define CHUNK 64   // cols per chunk

typedef __attribute__((ext_vector_type(8))) short bf16x8;
typedef __attribute__((ext_vector_type(4))) float f32x4;

// RNE f32 -> bf16 hi/lo split of 8 values
__device__ __forceinline__ void split8(float4 u, float4 v, bf16x8& h, bf16x8& l) {
    float f[8] = {u.x, u.y, u.z, u.w, v.x, v.y, v.z, v.w};
#pragma unroll
    for (int j = 0; j < 8; ++j) {
        uint32_t b = __float_as_uint(f[j]);
        uint32_t hb = (b + 0x7fffu + ((b >> 16) & 1u)) & 0xffff0000u;
        float hf = __uint_as_float(hb);
        float r = f[j] - hf;
        uint32_t rb = __float_as_uint(r);
        uint32_t lb = (rb + 0x7fffu + ((rb >> 16) & 1u)) >> 16;
        h[j] = (short)(hb >> 16);
        l[j] = (short)lb;
    }
}

// ---- prep: e2[g][k] = sum_j embed^2 ; split embed into bf16 hi/lo ----
__global__ void k_prep(const float* __restrict__ embed, float* __restrict__ e2,
                       ushort* __restrict__ eh, ushort* __restrict__ el) {
    int t = blockIdx.x * blockDim.x + threadIdx.x; // 0..GQ*KQ-1
    const float* row = embed + (size_t)t * dq;
    ushort* hrow = eh + (size_t)t * dq;
    ushort* lrow = el + (size_t)t * dq;
    float s = 0.f;
#pragma unroll 8
    for (int j = 0; j < dq; ++j) {
        float f = row[j];
        s = fmaf(f, f, s);
        uint32_t b = __float_as_uint(f);
        uint32_t hb = (b + 0x7fffu + ((b >> 16) & 1u)) & 0xffff0000u;
        float hf = __uint_as_float(hb);
        float r = f - hf;
        uint32_t rb = __float_as_uint(r);
        hrow[j] = (ushort)(hb >> 16);
        lrow[j] = (ushort)((rb + 0x7fffu + ((rb >> 16) & 1u)) >> 16);
    }
    e2[t] = s;
}

// ---- MFMA scores + fused top-2 argmax ----
__launch_bounds__(256)
__global__ void k_scores_mfma(const float* __restrict__ x,
                              const ushort* __restrict__ eh,
                              const ushort* __restrict__ el,
                              const float* __restrict__ e2,
                              int* __restrict__ ind_t,
                              int* __restrict__ ctr, int2* __restrict__ list) {
    int g = blockIdx.y;
    int n0 = blockIdx.x * MBLK;
    int wid = threadIdx.x >> 6;
    int lane = threadIdx.x & 63;
    int l15 = lane & 15, l4 = lane >> 4;

    __shared__ float cm1[NW][MBLK];
    __shared__ float cm2[NW][MBLK];
    __shared__ int   ckk[NW][MBLK];

    // A fragments: rows n0+m*16+l15, k = c*32 + l4*8 + j  (k == dim within group g)
    bf16x8 ah[4][2], al[4][2];
#pragma unroll
    for (int m = 0; m < 4; ++m)
#pragma unroll
        for (int c = 0; c < 2; ++c) {
            const float4* p = reinterpret_cast<const float4*>(
                x + (size_t)(n0 + m * 16 + l15) * DQ + g * dq + c * 32 + l4 * 8);
            split8(p[0], p[1], ah[m][c], al[m][c]);
        }

    const ushort* ehg = eh + (size_t)g * KQ * dq;
    const ushort* elg = el + (size_t)g * KQ * dq;
    const float*  e2g = e2 + (size_t)g * KQ;

    float m1[4][4], m2[4][4];
    int   k1[4][4];
#pragma unroll
    for (int m = 0; m < 4; ++m)
#pragma unroll
        for (int r = 0; r < 4; ++r) { m1[m][r] = -3.4e38f; m2[m][r] = -3.4e38f; k1[m][r] = 0; }

    int wbase = wid * WCOLS;
#pragma unroll
    for (int ch = 0; ch < 4; ++ch) {
        int cb = wbase + ch * CHUNK;
        f32x4 acc[4][4];
#pragma unroll
        for (int m = 0; m < 4; ++m)
#pragma unroll
            for (int n = 0; n < 4; ++n) acc[m][n] = (f32x4){0.f, 0.f, 0.f, 0.f};

#pragma unroll
        for (int c = 0; c < 2; ++c) {
            bf16x8 bh[4], bl[4];
#pragma unroll
            for (int n = 0; n < 4; ++n) {
                size_t off = (size_t)(cb + n * 16 + l15) * dq + c * 32 + l4 * 8;
                bh[n] = *reinterpret_cast<const bf16x8*>(ehg + off);
                bl[n] = *reinterpret_cast<const bf16x8*>(elg + off);
            }
#pragma unroll
            for (int m = 0; m < 4; ++m)
#pragma unroll
                for (int n = 0; n < 4; ++n) {
                    acc[m][n] = __builtin_amdgcn_mfma_f32_16x16x32_bf16(ah[m][c], bh[n], acc[m][n], 0, 0, 0);
                    acc[m][n] = __builtin_amdgcn_mfma_f32_16x16x32_bf16(ah[m][c], bl[n], acc[m][n], 0, 0, 0);
                    acc[m][n] = __builtin_amdgcn_mfma_f32_16x16x32_bf16(al[m][c], bh[n], acc[m][n], 0, 0, 0);
                }
        }
        // epilogue: s = 2*dot - e2 ; top-2 per (m,r)
#pragma unroll
        for (int n = 0; n < 4; ++n) {
            int col = cb + n * 16 + l15;
            float e2v = e2g[col];
#pragma unroll
            for (int m = 0; m < 4; ++m)
#pragma unroll
                for (int r = 0; r < 4; ++r) {
                    float s = fmaf(2.0f, acc[m][n][r], -e2v);
                    bool gt = s > m1[m][r];
                    float t = fmaxf(m2[m][r], s);
                    m2[m][r] = gt ? m1[m][r] : t;
                    k1[m][r] = gt ? col : k1[m][r];
                    m1[m][r] = fmaxf(m1[m][r], s);
                }
        }
    }

    // cross-lane reduce over the 16 col-lanes (same rows live at same l4 group)
#pragma unroll
    for (int m = 0; m < 4; ++m)
#pragma unroll
        for (int r = 0; r < 4; ++r) {
            float a1 = m1[m][r], a2 = m2[m][r];
            int ak = k1[m][r];
#pragma unroll
            for (int d = 1; d < 16; d <<= 1) {
                float o1 = __shfl_xor(a1, d, 64);
                float o2 = __shfl_xor(a2, d, 64);
                int   ok = __shfl_xor(ak, d, 64);
                bool sw = (o1 > a1) || (o1 == a1 && ok < ak);
                float big = sw ? o1 : a1;
                int bigk = sw ? ok : ak;
                float small = sw ? a1 : o1;
                a2 = fmaxf(fmaxf(a2, o2), small);
                a1 = big; ak = bigk;
            }
            if (l15 == 0) {
                int row = m * 16 + l4 * 4 + r;
                cm1[wid][row] = a1;
                cm2[wid][row] = a2;
                ckk[wid][row] = ak;
            }
        }
    __syncthreads();

    if (threadIdx.x < MBLK) {
        int row = threadIdx.x;
        float a1 = cm1[0][row], a2 = cm2[0][row];
        int ak = ckk[0][row];
#pragma unroll
        for (int w = 1; w < NW; ++w) {
            float o1 = cm1[w][row], o2 = cm2[w][row];
            int ok = ckk[w][row];
            bool sw = (o1 > a1) || (o1 == a1 && ok < ak);
            float big = sw ? o1 : a1;
            int bigk = sw ? ok : ak;
            float small = sw ? a1 : o1;
            a2 = fmaxf(fmaxf(a2, o2), small);
            a1 = big; ak = bigk;
        }
        ind_t[(size_t)g * NQ + n0 + row] = ak;
        if (a1 - a2 < MARGIN) {
            int idx = atomicAdd(ctr, 1);
            if (idx < CAP) list[idx] = make_int2(n0 + row, g);
        }
    }
}

// ---- f64 recheck of flagged queries ----
__launch_bounds__(256)
__global__ void k_recheck(const float* __restrict__ x, const float* __restrict__ embed,
                          const int* __restrict__ ctr, const int2* __restrict__ list,
                          int* __restrict__ ind_t) {
    __shared__ double sv[256];
    __shared__ int si[256];
    int nitems = *ctr;
    if (nitems > CAP) nitems = CAP;
    for (int it = blockIdx.x; it < nitems; it += gridDim.x) {
        int2 q = list[it];
        int n = q.x, g = q.y;
        const float* xrow = x + (size_t)n * DQ + g * dq;
        double best = -1e300;
        int bk = KQ;
        for (int k = threadIdx.x; k < KQ; k += 256) {
            const float* er = embed + ((size_t)g * KQ + k) * dq;
            double dot = 0.0, ee = 0.0;
#pragma unroll 8
            for (int j = 0; j < dq; ++j) {
                double ev = (double)er[j];
                dot = fma((double)xrow[j], ev, dot);
                ee = fma(ev, ev, ee);
            }
            double s = 2.0 * dot - ee;
            if (s > best || (s == best && k < bk)) { best = s; bk = k; }
        }
        sv[threadIdx.x] = best; si[threadIdx.x] = bk;
        __syncthreads();
        for (int off = 128; off > 0; off >>= 1) {
            if (threadIdx.x < off) {
                double ov = sv[threadIdx.x + off]; int oi = si[threadIdx.x + off];
                if (ov > sv[threadIdx.x] || (ov == sv[threadIdx.x] && oi < si[threadIdx.x])) {
                    sv[threadIdx.x] = ov; si[threadIdx.x] = oi;
                }
            }
            __syncthreads();
        }
        if (threadIdx.x == 0) ind_t[(size_t)g * NQ + n] = si[0];
        __syncthreads();
    }
}

// ---- zq gather + ind output ----
__global__ void k_gather(const float* __restrict__ embed, const int* __restrict__ ind_t,
                         float* __restrict__ zq, float* __restrict__ ind_out) {
    int t = blockIdx.x * 256 + threadIdx.x;   // float4 index
    int j4 = t & 15;
    int g = (t >> 4) & 3;
    int n = t >> 6;
    int k = ind_t[(size_t)g * NQ + n];
    const float4* e4 = reinterpret_cast<const float4*>(embed) + ((size_t)(g * KQ + k) * 16 + j4);
    reinterpret_cast<float4*>(zq)[t] = *e4;
    if (t < NQ * GQ) {
        int n2 = t >> 2, g2 = t & 3;
        ind_out[t] = (float)ind_t[(size_t)g2 * NQ + n2];
    }
}

// ---- deterministic segment sum ----
__launch_bounds__(64)
__global__ void k_segsum(const float* __restrict__ x, const int* __restrict__ ind_t,
                         const float* __restrict__ embed_avg, const float* __restrict__ cs,
                         float* __restrict__ out_cs, float* __restrict__ out_avg) {
    int gk = blockIdx.x;
    int g = gk >> 10, k = gk & 1023;
    int lane = threadIdx.x;
    const int* ip = ind_t + (size_t)g * NQ;
    float acc = 0.f;
    int cnt = 0;
    for (int n0 = 0; n0 < NQ; n0 += 64) {
        int v = ip[n0 + lane];
        unsigned long long mask = __ballot(v == k);
        cnt += __popcll(mask);
        while (mask) {
            int i = __ffsll(mask) - 1;
            mask &= mask - 1;
            acc += x[(size_t)(n0 + i) * DQ + g * dq + lane];
        }
    }
    float nea = DECAYF * embed_avg[(size_t)gk * dq + lane] + (1.0f - DECAYF) * acc;
    out_avg[(size_t)gk * dq + lane] = nea;
    if (lane == 0) out_cs[gk] = DECAYF * cs[gk] + (1.0f - DECAYF) * (float)cnt;
}

// ---- tot[g] ----
__global__ void k_tot(const float* __restrict__ out_cs, float* __restrict__ tot) {
    int g = blockIdx.x;
    __shared__ float red[256];
    float s = 0.f;
    for (int k = threadIdx.x; k < KQ; k += 256) s += out_cs[g * KQ + k];
    red[threadIdx.x] = s;
    __syncthreads();
    for (int off = 128; off > 0; off >>= 1) {
        if (threadIdx.x < off) red[threadIdx.x] += red[threadIdx.x + off];
        __syncthreads();
    }
    if (threadIdx.x == 0) tot[g] = red[0];
}

// ---- new_embed ----
__global__ void k_embed(const float* __restrict__ out_avg, const float* __restrict__ out_cs,
                        const float* __restrict__ tot, float* __restrict__ out_embed) {
    int t = blockIdx.x * 256 + threadIdx.x;
    int gk = t >> 6;
    int g = gk >> 10;
    double ncs = (double)out_cs[gk];
    double tt = (double)tot[g];
    double sm = (ncs + (double)EPSF) / (tt + (double)KQ * (double)EPSF) * tt;
    out_embed[t] = (float)((double)out_avg[t] / sm);
}

extern "C" void kernel_launch(void* const* d_in, const int* in_sizes, int n_in,
                              void* d_out, int out_size, void* d_ws, size_t ws_size,
                              hipStream_t stream) {
    const float* x         = (const float*)d_in[0];
    const float* embed     = (const float*)d_in[1];
    const float* embed_avg = (const float*)d_in[2];
    const float* cs        = (const float*)d_in[3];
    float* out = (float*)d_out;
    float* zq        = out + OFF_ZQ;
    float* ind_out   = out + OFF_IND;
    float* out_embed = out + OFF_EMB;
    float* out_cs    = out + OFF_CS;
    float* out_avg   = out + OFF_AVG;

    char* ws = (char*)d_ws;
    int*    ind_t = (int*)(ws + WS_IND);
    float*  e2    = (float*)(ws + WS_E2);
    ushort* eh    = (ushort*)(ws + WS_EH);
    ushort* el    = (ushort*)(ws + WS_EL);
    float*  tot   = (float*)(ws + WS_TOT);
    int*    ctr   = (int*)(ws + WS_CTR);
    int2*   list  = (int2*)(ws + WS_LIST);

    hipMemsetAsync(ctr, 0, sizeof(int), stream);
    k_prep<<<GQ * KQ / 256, 256, 0, stream>>>(embed, e2, eh, el);
    dim3 g1(NQ / MBLK, GQ);
    k_scores_mfma<<<g1, 256, 0, stream>>>(x, eh, el, e2, ind_t, ctr, list);
    k_recheck<<<256, 256, 0, stream>>>(x, embed, ctr, list, ind_t);
    k_gather<<<(NQ * GQ * 16) / 256, 256, 0, stream>>>(embed, ind_t, zq, ind_out);
    k_segsum<<<GQ * KQ, 64, 0, stream>>>(x, ind_t, embed_avg, cs, out_cs, out_avg);
    k_tot<<<GQ, 256, 0, stream>>>(out_cs, tot);
    k_embed<<<(GQ * KQ * dq) / 256, 256, 0, stream>>>(out_avg, out_cs, tot, out_embed);
}

// Round 3
// 279.534 us; speedup vs baseline: 5.5114x; 2.0519x over previous
//
#include <hip/hip_runtime.h>
#include <cstdint>

// Problem constants
#define GQ 4
#define KQ 1024
#define DQ 256     // = GQ * dq
#define dq 64
#define NQ 32768   // B*S = 8*4096
#define DECAYF 0.99f
#define EPSF 1e-5f

// Output flat offsets (floats)
#define OFF_ZQ    0
#define OFF_IND   8388608
#define OFF_EMB   8519680
#define OFF_CS    8781824
#define OFF_AVG   8785920

// Workspace layout (bytes)
#define WS_IND   0              // int32 [GQ][NQ]  (transposed ind)
#define WS_E2    524288         // float [GQ][KQ]
#define WS_EH    540672         // ushort(bf16) [GQ][KQ][dq]  embed hi
#define WS_EL    1064960        // ushort(bf16) [GQ][KQ][dq]  embed lo
#define WS_TOT   1589248        // float [GQ]
#define WS_CTR   1589264        // int
#define WS_LIST  1589280        // int2 [CAP]
#define CAP      16384

#define MARGIN 0.02f

#define MBLK 64    // rows per block
#define NW 4       // waves per block
#define WCOLS 256  // cols per wave
#define CHUNK 64   // cols per chunk

typedef __attribute__((ext_vector_type(8))) short bf16x8;
typedef __attribute__((ext_vector_type(4))) float f32x4;

// RNE f32 -> bf16 hi/lo split of 8 values
__device__ __forceinline__ void split8(float4 u, float4 v, bf16x8& h, bf16x8& l) {
    float f[8] = {u.x, u.y, u.z, u.w, v.x, v.y, v.z, v.w};
#pragma unroll
    for (int j = 0; j < 8; ++j) {
        uint32_t b = __float_as_uint(f[j]);
        uint32_t hb = (b + 0x7fffu + ((b >> 16) & 1u)) & 0xffff0000u;
        float hf = __uint_as_float(hb);
        float r = f[j] - hf;
        uint32_t rb = __float_as_uint(r);
        uint32_t lb = (rb + 0x7fffu + ((rb >> 16) & 1u)) >> 16;
        h[j] = (short)(hb >> 16);
        l[j] = (short)lb;
    }
}

// ---- prep: e2[g][k] = sum_j embed^2 ; split embed into bf16 hi/lo ----
__global__ void k_prep(const float* __restrict__ embed, float* __restrict__ e2,
                       ushort* __restrict__ eh, ushort* __restrict__ el) {
    int t = blockIdx.x * blockDim.x + threadIdx.x; // 0..GQ*KQ-1
    const float* row = embed + (size_t)t * dq;
    ushort* hrow = eh + (size_t)t * dq;
    ushort* lrow = el + (size_t)t * dq;
    float s = 0.f;
#pragma unroll 8
    for (int j = 0; j < dq; ++j) {
        float f = row[j];
        s = fmaf(f, f, s);
        uint32_t b = __float_as_uint(f);
        uint32_t hb = (b + 0x7fffu + ((b >> 16) & 1u)) & 0xffff0000u;
        float hf = __uint_as_float(hb);
        float r = f - hf;
        uint32_t rb = __float_as_uint(r);
        hrow[j] = (ushort)(hb >> 16);
        lrow[j] = (ushort)((rb + 0x7fffu + ((rb >> 16) & 1u)) >> 16);
    }
    e2[t] = s;
}

// ---- MFMA scores + fused top-2 argmax ----
__launch_bounds__(256)
__global__ void k_scores_mfma(const float* __restrict__ x,
                              const ushort* __restrict__ eh,
                              const ushort* __restrict__ el,
                              const float* __restrict__ e2,
                              int* __restrict__ ind_t,
                              int* __restrict__ ctr, int2* __restrict__ list) {
    int g = blockIdx.y;
    int n0 = blockIdx.x * MBLK;
    int wid = threadIdx.x >> 6;
    int lane = threadIdx.x & 63;
    int l15 = lane & 15, l4 = lane >> 4;

    __shared__ float cm1[NW][MBLK];
    __shared__ float cm2[NW][MBLK];
    __shared__ int   ckk[NW][MBLK];

    // A fragments: rows n0+m*16+l15, k = c*32 + l4*8 + j
    bf16x8 ah[4][2], al[4][2];
#pragma unroll
    for (int m = 0; m < 4; ++m)
#pragma unroll
        for (int c = 0; c < 2; ++c) {
            const float4* p = reinterpret_cast<const float4*>(
                x + (size_t)(n0 + m * 16 + l15) * DQ + g * dq + c * 32 + l4 * 8);
            split8(p[0], p[1], ah[m][c], al[m][c]);
        }

    const ushort* ehg = eh + (size_t)g * KQ * dq;
    const ushort* elg = el + (size_t)g * KQ * dq;
    const float*  e2g = e2 + (size_t)g * KQ;

    float m1[4][4], m2[4][4];
    int   k1[4][4];
#pragma unroll
    for (int m = 0; m < 4; ++m)
#pragma unroll
        for (int r = 0; r < 4; ++r) { m1[m][r] = -3.4e38f; m2[m][r] = -3.4e38f; k1[m][r] = 0; }

    int wbase = wid * WCOLS;
#pragma unroll
    for (int ch = 0; ch < 4; ++ch) {
        int cb = wbase + ch * CHUNK;
        f32x4 acc[4][4];
#pragma unroll
        for (int m = 0; m < 4; ++m)
#pragma unroll
            for (int n = 0; n < 4; ++n) acc[m][n] = (f32x4){0.f, 0.f, 0.f, 0.f};

#pragma unroll
        for (int c = 0; c < 2; ++c) {
            bf16x8 bh[4], bl[4];
#pragma unroll
            for (int n = 0; n < 4; ++n) {
                size_t off = (size_t)(cb + n * 16 + l15) * dq + c * 32 + l4 * 8;
                bh[n] = *reinterpret_cast<const bf16x8*>(ehg + off);
                bl[n] = *reinterpret_cast<const bf16x8*>(elg + off);
            }
#pragma unroll
            for (int m = 0; m < 4; ++m)
#pragma unroll
                for (int n = 0; n < 4; ++n) {
                    acc[m][n] = __builtin_amdgcn_mfma_f32_16x16x32_bf16(ah[m][c], bh[n], acc[m][n], 0, 0, 0);
                    acc[m][n] = __builtin_amdgcn_mfma_f32_16x16x32_bf16(ah[m][c], bl[n], acc[m][n], 0, 0, 0);
                    acc[m][n] = __builtin_amdgcn_mfma_f32_16x16x32_bf16(al[m][c], bh[n], acc[m][n], 0, 0, 0);
                }
        }
        // epilogue: s = 2*dot - e2 ; top-2 per (m,r); med3 = second-max update
#pragma unroll
        for (int n = 0; n < 4; ++n) {
            int col = cb + n * 16 + l15;
            float e2v = e2g[col];
#pragma unroll
            for (int m = 0; m < 4; ++m)
#pragma unroll
                for (int r = 0; r < 4; ++r) {
                    float s = fmaf(2.0f, acc[m][n][r], -e2v);
                    bool gt = s > m1[m][r];
                    m2[m][r] = __builtin_amdgcn_fmed3f(s, m1[m][r], m2[m][r]);
                    k1[m][r] = gt ? col : k1[m][r];
                    m1[m][r] = fmaxf(m1[m][r], s);
                }
        }
    }

    // cross-lane reduce over the 16 col-lanes
#pragma unroll
    for (int m = 0; m < 4; ++m)
#pragma unroll
        for (int r = 0; r < 4; ++r) {
            float a1 = m1[m][r], a2 = m2[m][r];
            int ak = k1[m][r];
#pragma unroll
            for (int d = 1; d < 16; d <<= 1) {
                float o1 = __shfl_xor(a1, d, 64);
                float o2 = __shfl_xor(a2, d, 64);
                int   ok = __shfl_xor(ak, d, 64);
                bool sw = (o1 > a1) || (o1 == a1 && ok < ak);
                float big = sw ? o1 : a1;
                int bigk = sw ? ok : ak;
                float small = sw ? a1 : o1;
                a2 = fmaxf(fmaxf(a2, o2), small);
                a1 = big; ak = bigk;
            }
            if (l15 == 0) {
                int row = m * 16 + l4 * 4 + r;
                cm1[wid][row] = a1;
                cm2[wid][row] = a2;
                ckk[wid][row] = ak;
            }
        }
    __syncthreads();

    if (threadIdx.x < MBLK) {
        int row = threadIdx.x;
        float a1 = cm1[0][row], a2 = cm2[0][row];
        int ak = ckk[0][row];
#pragma unroll
        for (int w = 1; w < NW; ++w) {
            float o1 = cm1[w][row], o2 = cm2[w][row];
            int ok = ckk[w][row];
            bool sw = (o1 > a1) || (o1 == a1 && ok < ak);
            float big = sw ? o1 : a1;
            int bigk = sw ? ok : ak;
            float small = sw ? a1 : o1;
            a2 = fmaxf(fmaxf(a2, o2), small);
            a1 = big; ak = bigk;
        }
        ind_t[(size_t)g * NQ + n0 + row] = ak;
        if (a1 - a2 < MARGIN) {
            int idx = atomicAdd(ctr, 1);
            if (idx < CAP) list[idx] = make_int2(n0 + row, g);
        }
    }
}

// ---- f64 recheck of flagged queries ----
__launch_bounds__(256)
__global__ void k_recheck(const float* __restrict__ x, const float* __restrict__ embed,
                          const int* __restrict__ ctr, const int2* __restrict__ list,
                          int* __restrict__ ind_t) {
    __shared__ double sv[256];
    __shared__ int si[256];
    int nitems = *ctr;
    if (nitems > CAP) nitems = CAP;
    for (int it = blockIdx.x; it < nitems; it += gridDim.x) {
        int2 q = list[it];
        int n = q.x, g = q.y;
        const float* xrow = x + (size_t)n * DQ + g * dq;
        double best = -1e300;
        int bk = KQ;
        for (int k = threadIdx.x; k < KQ; k += 256) {
            const float* er = embed + ((size_t)g * KQ + k) * dq;
            double dot = 0.0, ee = 0.0;
#pragma unroll 8
            for (int j = 0; j < dq; ++j) {
                double ev = (double)er[j];
                dot = fma((double)xrow[j], ev, dot);
                ee = fma(ev, ev, ee);
            }
            double s = 2.0 * dot - ee;
            if (s > best || (s == best && k < bk)) { best = s; bk = k; }
        }
        sv[threadIdx.x] = best; si[threadIdx.x] = bk;
        __syncthreads();
        for (int off = 128; off > 0; off >>= 1) {
            if (threadIdx.x < off) {
                double ov = sv[threadIdx.x + off]; int oi = si[threadIdx.x + off];
                if (ov > sv[threadIdx.x] || (ov == sv[threadIdx.x] && oi < si[threadIdx.x])) {
                    sv[threadIdx.x] = ov; si[threadIdx.x] = oi;
                }
            }
            __syncthreads();
        }
        if (threadIdx.x == 0) ind_t[(size_t)g * NQ + n] = si[0];
        __syncthreads();
    }
}

// ---- zq gather + ind output ----
__global__ void k_gather(const float* __restrict__ embed, const int* __restrict__ ind_t,
                         float* __restrict__ zq, float* __restrict__ ind_out) {
    int t = blockIdx.x * 256 + threadIdx.x;   // float4 index
    int j4 = t & 15;
    int g = (t >> 4) & 3;
    int n = t >> 6;
    int k = ind_t[(size_t)g * NQ + n];
    const float4* e4 = reinterpret_cast<const float4*>(embed) + ((size_t)(g * KQ + k) * 16 + j4);
    reinterpret_cast<float4*>(zq)[t] = *e4;
    if (t < NQ * GQ) {
        int n2 = t >> 2, g2 = t & 3;
        ind_out[t] = (float)ind_t[(size_t)g2 * NQ + n2];
    }
}

// ---- segment sum v2: 8 bins/block, 8 waves split the N-scan, LDS accumulate ----
#define SB 8   // bins per block
#define SW 8   // waves per block
__launch_bounds__(512)
__global__ void k_segsum2(const float* __restrict__ x, const int* __restrict__ ind_t,
                          const float* __restrict__ embed_avg, const float* __restrict__ cs,
                          float* __restrict__ out_cs, float* __restrict__ out_avg) {
    __shared__ float lacc[SW][SB][64];
    __shared__ int   lcnt[SW][SB];

    int g = blockIdx.x >> 7;            // 512 blocks: 4 g * 128
    int kbase = (blockIdx.x & 127) * SB;
    int wid = threadIdx.x >> 6;
    int lane = threadIdx.x & 63;

    // zero LDS
    for (int i = threadIdx.x; i < SW * SB * 64; i += 512) ((float*)lacc)[i] = 0.f;
    if (threadIdx.x < SW * SB) ((int*)lcnt)[threadIdx.x] = 0;
    __syncthreads();

    const int* ip = ind_t + (size_t)g * NQ;
    const float* xg = x + g * dq;
    int cnt0 = 0, cnt1 = 0, cnt2 = 0, cnt3 = 0, cnt4 = 0, cnt5 = 0, cnt6 = 0, cnt7 = 0;
    int wbase = wid * (NQ / SW);

    for (int n0 = wbase; n0 < wbase + NQ / SW; n0 += 256) {
        int v0 = ip[n0 + lane];
        int v1 = ip[n0 + 64 + lane];
        int v2 = ip[n0 + 128 + lane];
        int v3 = ip[n0 + 192 + lane];
#pragma unroll
        for (int u = 0; u < 4; ++u) {
            int v = u == 0 ? v0 : (u == 1 ? v1 : (u == 2 ? v2 : v3));
            int d = v - kbase;
            cnt0 += __popcll(__ballot(d == 0));
            cnt1 += __popcll(__ballot(d == 1));
            cnt2 += __popcll(__ballot(d == 2));
            cnt3 += __popcll(__ballot(d == 3));
            cnt4 += __popcll(__ballot(d == 4));
            cnt5 += __popcll(__ballot(d == 5));
            cnt6 += __popcll(__ballot(d == 6));
            cnt7 += __popcll(__ballot(d == 7));
            unsigned long long mask = __ballot((unsigned)d < (unsigned)SB);
            while (mask) {
                int i = __ffsll(mask) - 1;
                mask &= mask - 1;
                int b = __shfl(d, i, 64);        // uniform
                int nv = n0 + u * 64 + i;
                lacc[wid][b][lane] += xg[(size_t)nv * DQ + lane];
            }
        }
    }
    if (lane == 0) {
        lcnt[wid][0] = cnt0; lcnt[wid][1] = cnt1; lcnt[wid][2] = cnt2; lcnt[wid][3] = cnt3;
        lcnt[wid][4] = cnt4; lcnt[wid][5] = cnt5; lcnt[wid][6] = cnt6; lcnt[wid][7] = cnt7;
    }
    __syncthreads();

    // combine waves in fixed order (deterministic)
    int b = threadIdx.x >> 6;           // 0..7
    int l = threadIdx.x & 63;
    float a = 0.f;
#pragma unroll
    for (int w = 0; w < SW; ++w) a += lacc[w][b][l];
    int gk = g * KQ + kbase + b;
    float nea = DECAYF * embed_avg[(size_t)gk * dq + l] + (1.0f - DECAYF) * a;
    out_avg[(size_t)gk * dq + l] = nea;
    if (l == 0) {
        int c = 0;
#pragma unroll
        for (int w = 0; w < SW; ++w) c += lcnt[w][b];
        out_cs[gk] = DECAYF * cs[gk] + (1.0f - DECAYF) * (float)c;
    }
}

// ---- tot[g] ----
__global__ void k_tot(const float* __restrict__ out_cs, float* __restrict__ tot) {
    int g = blockIdx.x;
    __shared__ float red[256];
    float s = 0.f;
    for (int k = threadIdx.x; k < KQ; k += 256) s += out_cs[g * KQ + k];
    red[threadIdx.x] = s;
    __syncthreads();
    for (int off = 128; off > 0; off >>= 1) {
        if (threadIdx.x < off) red[threadIdx.x] += red[threadIdx.x + off];
        __syncthreads();
    }
    if (threadIdx.x == 0) tot[g] = red[0];
}

// ---- new_embed ----
__global__ void k_embed(const float* __restrict__ out_avg, const float* __restrict__ out_cs,
                        const float* __restrict__ tot, float* __restrict__ out_embed) {
    int t = blockIdx.x * 256 + threadIdx.x;
    int gk = t >> 6;
    int g = gk >> 10;
    double ncs = (double)out_cs[gk];
    double tt = (double)tot[g];
    double sm = (ncs + (double)EPSF) / (tt + (double)KQ * (double)EPSF) * tt;
    out_embed[t] = (float)((double)out_avg[t] / sm);
}

extern "C" void kernel_launch(void* const* d_in, const int* in_sizes, int n_in,
                              void* d_out, int out_size, void* d_ws, size_t ws_size,
                              hipStream_t stream) {
    const float* x         = (const float*)d_in[0];
    const float* embed     = (const float*)d_in[1];
    const float* embed_avg = (const float*)d_in[2];
    const float* cs        = (const float*)d_in[3];
    float* out = (float*)d_out;
    float* zq        = out + OFF_ZQ;
    float* ind_out   = out + OFF_IND;
    float* out_embed = out + OFF_EMB;
    float* out_cs    = out + OFF_CS;
    float* out_avg   = out + OFF_AVG;

    char* ws = (char*)d_ws;
    int*    ind_t = (int*)(ws + WS_IND);
    float*  e2    = (float*)(ws + WS_E2);
    ushort* eh    = (ushort*)(ws + WS_EH);
    ushort* el    = (ushort*)(ws + WS_EL);
    float*  tot   = (float*)(ws + WS_TOT);
    int*    ctr   = (int*)(ws + WS_CTR);
    int2*   list  = (int2*)(ws + WS_LIST);

    hipMemsetAsync(ctr, 0, sizeof(int), stream);
    k_prep<<<GQ * KQ / 256, 256, 0, stream>>>(embed, e2, eh, el);
    dim3 g1(NQ / MBLK, GQ);
    k_scores_mfma<<<g1, 256, 0, stream>>>(x, eh, el, e2, ind_t, ctr, list);
    k_recheck<<<256, 256, 0, stream>>>(x, embed, ctr, list, ind_t);
    k_gather<<<(NQ * GQ * 16) / 256, 256, 0, stream>>>(embed, ind_t, zq, ind_out);
    k_segsum2<<<512, 512, 0, stream>>>(x, ind_t, embed_avg, cs, out_cs, out_avg);
    k_tot<<<GQ, 256, 0, stream>>>(out_cs, tot);
    k_embed<<<(GQ * KQ * dq) / 256, 256, 0, stream>>>(out_avg, out_cs, tot, out_embed);
}

// Round 4
// 269.476 us; speedup vs baseline: 5.7171x; 1.0373x over previous
//
#include <hip/hip_runtime.h>
#include <cstdint>

// Problem constants
#define GQ 4
#define KQ 1024
#define DQ 256     // = GQ * dq
#define dq 64
#define NQ 32768   // B*S = 8*4096
#define DECAYF 0.99f
#define EPSF 1e-5f

// Output flat offsets (floats)
#define OFF_ZQ    0
#define OFF_IND   8388608
#define OFF_EMB   8519680
#define OFF_CS    8781824
#define OFF_AVG   8785920

// Workspace layout (bytes)
#define WS_IND   0              // int32 [GQ][NQ]  (transposed ind)
#define WS_E2    524288         // float [GQ][KQ]
#define WS_EH    540672         // ushort(bf16) [GQ][KQ][dq]  embed hi
#define WS_EL    1064960        // ushort(bf16) [GQ][KQ][dq]  embed lo
#define WS_TOT   1589248        // float [GQ]
#define WS_CTR   1589264        // int
#define WS_LIST  1589280        // int2 [CAP]
#define CAP      16384

#define MARGIN 0.02f

#define MBLK 64    // rows per block

typedef __attribute__((ext_vector_type(8))) short bf16x8;
typedef __attribute__((ext_vector_type(4))) float f32x4;

// cheap f32 -> bf16 hi/lo split of 8 values: hi = truncate, lo = RNE(residual)
__device__ __forceinline__ void split8_fast(float4 u, float4 v, bf16x8& h, bf16x8& l) {
    float f[8] = {u.x, u.y, u.z, u.w, v.x, v.y, v.z, v.w};
#pragma unroll
    for (int j = 0; j < 8; ++j) {
        uint32_t b = __float_as_uint(f[j]);
        uint32_t hb = b & 0xffff0000u;
        float r = f[j] - __uint_as_float(hb);
        uint32_t rb = __float_as_uint(r);
        h[j] = (short)(hb >> 16);
        l[j] = (short)((rb + 0x7fffu + ((rb >> 16) & 1u)) >> 16);
    }
}

// ---- prep: e2[g][k] = sum_j embed^2 ; split embed into bf16 hi/lo (RNE hi) ----
__global__ void k_prep(const float* __restrict__ embed, float* __restrict__ e2,
                       ushort* __restrict__ eh, ushort* __restrict__ el) {
    int t = blockIdx.x * blockDim.x + threadIdx.x; // 0..GQ*KQ-1
    const float* row = embed + (size_t)t * dq;
    ushort* hrow = eh + (size_t)t * dq;
    ushort* lrow = el + (size_t)t * dq;
    float s = 0.f;
#pragma unroll 8
    for (int j = 0; j < dq; ++j) {
        float f = row[j];
        s = fmaf(f, f, s);
        uint32_t b = __float_as_uint(f);
        uint32_t hb = (b + 0x7fffu + ((b >> 16) & 1u)) & 0xffff0000u;
        float hf = __uint_as_float(hb);
        float r = f - hf;
        uint32_t rb = __float_as_uint(r);
        hrow[j] = (ushort)(hb >> 16);
        lrow[j] = (ushort)((rb + 0x7fffu + ((rb >> 16) & 1u)) >> 16);
    }
    e2[t] = s;
}

// ---- MFMA scores + fused top-2 argmax ----
// 4 waves as 2x2: wr = row half (32 rows), wc = col half (512 cols)
__launch_bounds__(256, 3)
__global__ void k_scores_mfma(const float* __restrict__ x,
                              const ushort* __restrict__ eh,
                              const ushort* __restrict__ el,
                              const float* __restrict__ e2,
                              int* __restrict__ ind_t,
                              int* __restrict__ ctr, int2* __restrict__ list) {
    int g = blockIdx.y;
    int n0 = blockIdx.x * MBLK;
    int wid = threadIdx.x >> 6;
    int wr = wid >> 1, wc = wid & 1;
    int lane = threadIdx.x & 63;
    int l15 = lane & 15, l4 = lane >> 4;

    __shared__ float cm1[2][MBLK];
    __shared__ float cm2[2][MBLK];
    __shared__ int   ckk[2][MBLK];

    // A fragments: rows n0 + wr*32 + m*16 + l15, k = c*32 + l4*8 + j
    bf16x8 ah[2][2], al[2][2];
#pragma unroll
    for (int m = 0; m < 2; ++m)
#pragma unroll
        for (int c = 0; c < 2; ++c) {
            const float4* p = reinterpret_cast<const float4*>(
                x + (size_t)(n0 + wr * 32 + m * 16 + l15) * DQ + g * dq + c * 32 + l4 * 8);
            split8_fast(p[0], p[1], ah[m][c], al[m][c]);
        }

    const ushort* ehg = eh + (size_t)g * KQ * dq;
    const ushort* elg = el + (size_t)g * KQ * dq;
    const float*  e2g = e2 + (size_t)g * KQ;

    float m1[2][4], m2[2][4];
    int   k1[2][4];
#pragma unroll
    for (int m = 0; m < 2; ++m)
#pragma unroll
        for (int r = 0; r < 4; ++r) { m1[m][r] = -3.4e38f; m2[m][r] = -3.4e38f; k1[m][r] = 0; }

    int wbase = wc * 512;
#pragma unroll 1
    for (int ch = 0; ch < 8; ++ch) {
        int cb = wbase + ch * 64;
        f32x4 acc[2][4];
#pragma unroll
        for (int m = 0; m < 2; ++m)
#pragma unroll
            for (int n = 0; n < 4; ++n) acc[m][n] = (f32x4){0.f, 0.f, 0.f, 0.f};

#pragma unroll
        for (int c = 0; c < 2; ++c) {
            bf16x8 bh[4], bl[4];
#pragma unroll
            for (int n = 0; n < 4; ++n) {
                size_t off = (size_t)(cb + n * 16 + l15) * dq + c * 32 + l4 * 8;
                bh[n] = *reinterpret_cast<const bf16x8*>(ehg + off);
                bl[n] = *reinterpret_cast<const bf16x8*>(elg + off);
            }
#pragma unroll
            for (int m = 0; m < 2; ++m)
#pragma unroll
                for (int n = 0; n < 4; ++n) {
                    acc[m][n] = __builtin_amdgcn_mfma_f32_16x16x32_bf16(ah[m][c], bh[n], acc[m][n], 0, 0, 0);
                    acc[m][n] = __builtin_amdgcn_mfma_f32_16x16x32_bf16(ah[m][c], bl[n], acc[m][n], 0, 0, 0);
                    acc[m][n] = __builtin_amdgcn_mfma_f32_16x16x32_bf16(al[m][c], bh[n], acc[m][n], 0, 0, 0);
                }
        }
        // epilogue: s = 2*dot - e2 ; top-2 per (m,r)
#pragma unroll
        for (int n = 0; n < 4; ++n) {
            int col = cb + n * 16 + l15;
            float e2v = e2g[col];
#pragma unroll
            for (int m = 0; m < 2; ++m)
#pragma unroll
                for (int r = 0; r < 4; ++r) {
                    float s = fmaf(2.0f, acc[m][n][r], -e2v);
                    bool gt = s > m1[m][r];
                    m2[m][r] = __builtin_amdgcn_fmed3f(s, m1[m][r], m2[m][r]);
                    k1[m][r] = gt ? col : k1[m][r];
                    m1[m][r] = fmaxf(m1[m][r], s);
                }
        }
    }

    // cross-lane reduce over the 16 col-lanes
#pragma unroll
    for (int m = 0; m < 2; ++m)
#pragma unroll
        for (int r = 0; r < 4; ++r) {
            float a1 = m1[m][r], a2 = m2[m][r];
            int ak = k1[m][r];
#pragma unroll
            for (int d = 1; d < 16; d <<= 1) {
                float o1 = __shfl_xor(a1, d, 64);
                float o2 = __shfl_xor(a2, d, 64);
                int   ok = __shfl_xor(ak, d, 64);
                bool sw = (o1 > a1) || (o1 == a1 && ok < ak);
                float big = sw ? o1 : a1;
                int bigk = sw ? ok : ak;
                float small = sw ? a1 : o1;
                a2 = fmaxf(fmaxf(a2, o2), small);
                a1 = big; ak = bigk;
            }
            if (l15 == 0) {
                int row = wr * 32 + m * 16 + l4 * 4 + r;   // 0..63
                cm1[wc][row] = a1;
                cm2[wc][row] = a2;
                ckk[wc][row] = ak;
            }
        }
    __syncthreads();

    if (threadIdx.x < MBLK) {
        int row = threadIdx.x;
        float a1 = cm1[0][row], a2 = cm2[0][row];
        int ak = ckk[0][row];
        {
            float o1 = cm1[1][row], o2 = cm2[1][row];
            int ok = ckk[1][row];
            bool sw = (o1 > a1) || (o1 == a1 && ok < ak);
            float big = sw ? o1 : a1;
            int bigk = sw ? ok : ak;
            float small = sw ? a1 : o1;
            a2 = fmaxf(fmaxf(a2, o2), small);
            a1 = big; ak = bigk;
        }
        ind_t[(size_t)g * NQ + n0 + row] = ak;
        if (a1 - a2 < MARGIN) {
            int idx = atomicAdd(ctr, 1);
            if (idx < CAP) list[idx] = make_int2(n0 + row, g);
        }
    }
}

// ---- f64 recheck of flagged queries ----
__launch_bounds__(256)
__global__ void k_recheck(const float* __restrict__ x, const float* __restrict__ embed,
                          const int* __restrict__ ctr, const int2* __restrict__ list,
                          int* __restrict__ ind_t) {
    __shared__ double sv[256];
    __shared__ int si[256];
    int nitems = *ctr;
    if (nitems > CAP) nitems = CAP;
    for (int it = blockIdx.x; it < nitems; it += gridDim.x) {
        int2 q = list[it];
        int n = q.x, g = q.y;
        const float* xrow = x + (size_t)n * DQ + g * dq;
        double best = -1e300;
        int bk = KQ;
        for (int k = threadIdx.x; k < KQ; k += 256) {
            const float* er = embed + ((size_t)g * KQ + k) * dq;
            double dot = 0.0, ee = 0.0;
#pragma unroll 8
            for (int j = 0; j < dq; ++j) {
                double ev = (double)er[j];
                dot = fma((double)xrow[j], ev, dot);
                ee = fma(ev, ev, ee);
            }
            double s = 2.0 * dot - ee;
            if (s > best || (s == best && k < bk)) { best = s; bk = k; }
        }
        sv[threadIdx.x] = best; si[threadIdx.x] = bk;
        __syncthreads();
        for (int off = 128; off > 0; off >>= 1) {
            if (threadIdx.x < off) {
                double ov = sv[threadIdx.x + off]; int oi = si[threadIdx.x + off];
                if (ov > sv[threadIdx.x] || (ov == sv[threadIdx.x] && oi < si[threadIdx.x])) {
                    sv[threadIdx.x] = ov; si[threadIdx.x] = oi;
                }
            }
            __syncthreads();
        }
        if (threadIdx.x == 0) ind_t[(size_t)g * NQ + n] = si[0];
        __syncthreads();
    }
}

// ---- zq gather + ind output ----
__global__ void k_gather(const float* __restrict__ embed, const int* __restrict__ ind_t,
                         float* __restrict__ zq, float* __restrict__ ind_out) {
    int t = blockIdx.x * 256 + threadIdx.x;   // float4 index
    int j4 = t & 15;
    int g = (t >> 4) & 3;
    int n = t >> 6;
    int k = ind_t[(size_t)g * NQ + n];
    const float4* e4 = reinterpret_cast<const float4*>(embed) + ((size_t)(g * KQ + k) * 16 + j4);
    reinterpret_cast<float4*>(zq)[t] = *e4;
    if (t < NQ * GQ) {
        int n2 = t >> 2, g2 = t & 3;
        ind_out[t] = (float)ind_t[(size_t)g2 * NQ + n2];
    }
}

// ---- segment sum v2: 8 bins/block, 8 waves split the N-scan, LDS accumulate ----
#define SB 8   // bins per block
#define SW 8   // waves per block
__launch_bounds__(512)
__global__ void k_segsum2(const float* __restrict__ x, const int* __restrict__ ind_t,
                          const float* __restrict__ embed_avg, const float* __restrict__ cs,
                          float* __restrict__ out_cs, float* __restrict__ out_avg) {
    __shared__ float lacc[SW][SB][64];
    __shared__ int   lcnt[SW][SB];

    int g = blockIdx.x >> 7;            // 512 blocks: 4 g * 128
    int kbase = (blockIdx.x & 127) * SB;
    int wid = threadIdx.x >> 6;
    int lane = threadIdx.x & 63;

    for (int i = threadIdx.x; i < SW * SB * 64; i += 512) ((float*)lacc)[i] = 0.f;
    if (threadIdx.x < SW * SB) ((int*)lcnt)[threadIdx.x] = 0;
    __syncthreads();

    const int* ip = ind_t + (size_t)g * NQ;
    const float* xg = x + g * dq;
    int cnt0 = 0, cnt1 = 0, cnt2 = 0, cnt3 = 0, cnt4 = 0, cnt5 = 0, cnt6 = 0, cnt7 = 0;
    int wbase = wid * (NQ / SW);

    for (int n0 = wbase; n0 < wbase + NQ / SW; n0 += 256) {
        int v0 = ip[n0 + lane];
        int v1 = ip[n0 + 64 + lane];
        int v2 = ip[n0 + 128 + lane];
        int v3 = ip[n0 + 192 + lane];
#pragma unroll
        for (int u = 0; u < 4; ++u) {
            int v = u == 0 ? v0 : (u == 1 ? v1 : (u == 2 ? v2 : v3));
            int d = v - kbase;
            cnt0 += __popcll(__ballot(d == 0));
            cnt1 += __popcll(__ballot(d == 1));
            cnt2 += __popcll(__ballot(d == 2));
            cnt3 += __popcll(__ballot(d == 3));
            cnt4 += __popcll(__ballot(d == 4));
            cnt5 += __popcll(__ballot(d == 5));
            cnt6 += __popcll(__ballot(d == 6));
            cnt7 += __popcll(__ballot(d == 7));
            unsigned long long mask = __ballot((unsigned)d < (unsigned)SB);
            while (mask) {
                int i = __ffsll(mask) - 1;
                mask &= mask - 1;
                int b = __shfl(d, i, 64);        // uniform
                int nv = n0 + u * 64 + i;
                lacc[wid][b][lane] += xg[(size_t)nv * DQ + lane];
            }
        }
    }
    if (lane == 0) {
        lcnt[wid][0] = cnt0; lcnt[wid][1] = cnt1; lcnt[wid][2] = cnt2; lcnt[wid][3] = cnt3;
        lcnt[wid][4] = cnt4; lcnt[wid][5] = cnt5; lcnt[wid][6] = cnt6; lcnt[wid][7] = cnt7;
    }
    __syncthreads();

    int b = threadIdx.x >> 6;           // 0..7
    int l = threadIdx.x & 63;
    float a = 0.f;
#pragma unroll
    for (int w = 0; w < SW; ++w) a += lacc[w][b][l];
    int gk = g * KQ + kbase + b;
    float nea = DECAYF * embed_avg[(size_t)gk * dq + l] + (1.0f - DECAYF) * a;
    out_avg[(size_t)gk * dq + l] = nea;
    if (l == 0) {
        int c = 0;
#pragma unroll
        for (int w = 0; w < SW; ++w) c += lcnt[w][b];
        out_cs[gk] = DECAYF * cs[gk] + (1.0f - DECAYF) * (float)c;
    }
}

// ---- tot[g] ----
__global__ void k_tot(const float* __restrict__ out_cs, float* __restrict__ tot) {
    int g = blockIdx.x;
    __shared__ float red[256];
    float s = 0.f;
    for (int k = threadIdx.x; k < KQ; k += 256) s += out_cs[g * KQ + k];
    red[threadIdx.x] = s;
    __syncthreads();
    for (int off = 128; off > 0; off >>= 1) {
        if (threadIdx.x < off) red[threadIdx.x] += red[threadIdx.x + off];
        __syncthreads();
    }
    if (threadIdx.x == 0) tot[g] = red[0];
}

// ---- new_embed ----
__global__ void k_embed(const float* __restrict__ out_avg, const float* __restrict__ out_cs,
                        const float* __restrict__ tot, float* __restrict__ out_embed) {
    int t = blockIdx.x * 256 + threadIdx.x;
    int gk = t >> 6;
    int g = gk >> 10;
    double ncs = (double)out_cs[gk];
    double tt = (double)tot[g];
    double sm = (ncs + (double)EPSF) / (tt + (double)KQ * (double)EPSF) * tt;
    out_embed[t] = (float)((double)out_avg[t] / sm);
}

extern "C" void kernel_launch(void* const* d_in, const int* in_sizes, int n_in,
                              void* d_out, int out_size, void* d_ws, size_t ws_size,
                              hipStream_t stream) {
    const float* x         = (const float*)d_in[0];
    const float* embed     = (const float*)d_in[1];
    const float* embed_avg = (const float*)d_in[2];
    const float* cs        = (const float*)d_in[3];
    float* out = (float*)d_out;
    float* zq        = out + OFF_ZQ;
    float* ind_out   = out + OFF_IND;
    float* out_embed = out + OFF_EMB;
    float* out_cs    = out + OFF_CS;
    float* out_avg   = out + OFF_AVG;

    char* ws = (char*)d_ws;
    int*    ind_t = (int*)(ws + WS_IND);
    float*  e2    = (float*)(ws + WS_E2);
    ushort* eh    = (ushort*)(ws + WS_EH);
    ushort* el    = (ushort*)(ws + WS_EL);
    float*  tot   = (float*)(ws + WS_TOT);
    int*    ctr   = (int*)(ws + WS_CTR);
    int2*   list  = (int2*)(ws + WS_LIST);

    hipMemsetAsync(ctr, 0, sizeof(int), stream);
    k_prep<<<GQ * KQ / 256, 256, 0, stream>>>(embed, e2, eh, el);
    dim3 g1(NQ / MBLK, GQ);
    k_scores_mfma<<<g1, 256, 0, stream>>>(x, eh, el, e2, ind_t, ctr, list);
    k_recheck<<<256, 256, 0, stream>>>(x, embed, ctr, list, ind_t);
    k_gather<<<(NQ * GQ * 16) / 256, 256, 0, stream>>>(embed, ind_t, zq, ind_out);
    k_segsum2<<<512, 512, 0, stream>>>(x, ind_t, embed_avg, cs, out_cs, out_avg);
    k_tot<<<GQ, 256, 0, stream>>>(out_cs, tot);
    k_embed<<<(GQ * KQ * dq) / 256, 256, 0, stream>>>(out_avg, out_cs, tot, out_embed);
}